// Round 1
// baseline (129.627 us; speedup 1.0000x reference)
//
#include <hip/hip_runtime.h>
#include <math.h>

#define D 3072
#define BATCH 512
#define NCLS 100
#define RC12 256          // row-chunks of 12 rows (colsum partial depth)
#define KS 96             // split-k chunks of 32 columns each

typedef __attribute__((ext_vector_type(8))) short bf16x8;
typedef __attribute__((ext_vector_type(4))) float f32x4;

// ws byte layout (fast path):
//   0        : pws    f32 [2][256][3072]  colsum partials      6291456 B
//   6291456  : csF    f32 [2][3072]       final colsums          24576 B
//   6316032  : Wb     bf16 [112][3072]    fc_w in bf16          688128 B
//   7004160  : part   f32 [96][512][100]  split-k partials    19660800 B
#define WS_OFF_CS  6291456ULL
#define WS_OFF_W   6316032ULL
#define WS_OFF_P   7004160ULL
#define WS_NEED    (WS_OFF_P + (size_t)KS * BATCH * NCLS * 4)

__device__ inline unsigned short f2bf(float f) {
    unsigned u = __float_as_uint(f);
    u += 0x7FFF + ((u >> 16) & 1);          // round-to-nearest-even
    return (unsigned short)(u >> 16);
}
__device__ inline float bf2f(unsigned short s) {
    return __uint_as_float(((unsigned)s) << 16);
}

// ---------------------------------------------------------------------------
// D1 "prep": 936 blocks.
//  blocks [0,768):   colsum partials, 12 rows x 1024 cols each, depth-256.
//                    ~14 waves/CU streaming a+b (75.5 MB) at HBM rate.
//  blocks [768,936): fc_w fp32 [100][3072] -> bf16 [112][3072] (pad rows 0),
//                    2 float4 items per thread.
// ---------------------------------------------------------------------------
__global__ __launch_bounds__(256) void prep_kernel(const float* __restrict__ a,
                                                   const float* __restrict__ b,
                                                   const float* __restrict__ fcw,
                                                   float* __restrict__ pws,
                                                   unsigned short* __restrict__ Wb) {
    const int bid = blockIdx.x;
    const int t   = threadIdx.x;
    if (bid < 768) {
        const int rc   = bid / 3;
        const int cg   = bid % 3;
        const int col  = cg * 1024 + t * 4;
        const int row0 = rc * 12;
        float4 sa = make_float4(0.f, 0.f, 0.f, 0.f);
        float4 sb = make_float4(0.f, 0.f, 0.f, 0.f);
        #pragma unroll
        for (int r = 0; r < 12; ++r) {
            const int i = row0 + r;
            const float4 va = *(const float4*)(a + (size_t)i * D + col);
            const float4 vb = *(const float4*)(b + (size_t)i * D + col);
            sa.x += va.x; sa.y += va.y; sa.z += va.z; sa.w += va.w;
            sb.x += vb.x; sb.y += vb.y; sb.z += vb.z; sb.w += vb.w;
        }
        *(float4*)(pws + (size_t)rc * D + col)          = sa;
        *(float4*)(pws + (size_t)(RC12 + rc) * D + col) = sb;
    } else {
        const int base = ((bid - 768) * 256 + t) * 2;   // float4-item index
        #pragma unroll
        for (int u = 0; u < 2; ++u) {
            const int idx = base + u;                   // 0..86015
            const int c   = idx / (D / 4);
            const int d   = (idx % (D / 4)) * 4;
            ushort4 o;
            if (c < NCLS) {
                const float4 v = *(const float4*)(fcw + (size_t)c * D + d);
                o.x = f2bf(v.x); o.y = f2bf(v.y); o.z = f2bf(v.z); o.w = f2bf(v.w);
            } else {
                o.x = o.y = o.z = o.w = 0;
            }
            *(ushort4*)(Wb + (size_t)c * D + d) = o;
        }
    }
}

// ---------------------------------------------------------------------------
// D2 "csred": reduce depth-256 partials to final colsum [2][3072].
// 4-lane team per output: each lane sums 64 planes, then shfl_xor combine.
// 96 blocks x 256 threads = 24576 = 6144 outputs x 4.
// ---------------------------------------------------------------------------
__global__ __launch_bounds__(256) void csred_kernel(const float* __restrict__ pws,
                                                    float* __restrict__ csF) {
    const int tid = blockIdx.x * 256 + threadIdx.x;    // 0..24575
    const int i   = tid >> 2;                          // output 0..6143
    const int g   = tid & 3;                           // depth group
    const int a2  = i / D;
    const int col = i % D;
    const float* p = pws + (size_t)(a2 * RC12 + g * 64) * D + col;
    float s = 0.f;
    #pragma unroll 8
    for (int rc = 0; rc < 64; ++rc)
        s += p[(size_t)rc * D];
    s += __shfl_xor(s, 1);
    s += __shfl_xor(s, 2);
    if (g == 0) csF[(size_t)a2 * D + col] = s;
}

// ---------------------------------------------------------------------------
// D3 "fzgemm": fused Z-gen + MFMA GEMM, split-K=96, NO LDS, NO prologue.
// Grid (8, 96) x 256 = 768 blocks (12 waves/CU). Each wave: one 16-row x
// 32-col chunk: Z = part1 + cos(x)*A + sin(x)*B on the fly into the A-frag,
// part[j] += Z_chunk x Wb^T via 16x16x32 bf16 MFMA. f32 partials.
// A/B frag: lane&15 = row/col, k=(lane>>4)*8+j. C/D: col=lane&15,
// row=(lane>>4)*4+reg  [verified earlier session].
// ---------------------------------------------------------------------------
__global__ __launch_bounds__(256) void fzgemm_kernel(
        const float* __restrict__ x,
        const float* __restrict__ w5,
        const float* __restrict__ n5,
        const float* __restrict__ csF,              // [2][3072] final colsums
        const unsigned short* __restrict__ Wb,      // [112][3072] bf16
        float* __restrict__ part) {                 // [KS][512][100] f32
    const int t    = threadIdx.x;
    const int wave = t >> 6;
    const int lane = t & 63;
    const int l16  = lane & 15;
    const int quad = lane >> 4;
    const int m0   = blockIdx.x * 64 + wave * 16;   // m-tile base (16 rows)
    const int j    = blockIdx.y;                    // k-chunk (32 cols)
    const int gcol = j * 32 + quad * 8;             // this lane's col base

    float part1 = 0.f;
    #pragma unroll
    for (int i = 0; i < 4; ++i)
        part1 += w5[i + 1] * n5[i + 1] + w5[i] * n5[i];

    const float4 Av0 = *(const float4*)(csF + gcol);
    const float4 Av1 = *(const float4*)(csF + gcol + 4);
    const float4 Bv0 = *(const float4*)(csF + D + gcol);
    const float4 Bv1 = *(const float4*)(csF + D + gcol + 4);

    const float* xr = x + (size_t)(m0 + l16) * D;
    const float4 xv0 = *(const float4*)(xr + gcol);
    const float4 xv1 = *(const float4*)(xr + gcol + 4);

    union { bf16x8 v; unsigned short s[8]; } af;
    float sv, cv;
    __sincosf(xv0.x, &sv, &cv); af.s[0] = f2bf(part1 + cv * Av0.x + sv * Bv0.x);
    __sincosf(xv0.y, &sv, &cv); af.s[1] = f2bf(part1 + cv * Av0.y + sv * Bv0.y);
    __sincosf(xv0.z, &sv, &cv); af.s[2] = f2bf(part1 + cv * Av0.z + sv * Bv0.z);
    __sincosf(xv0.w, &sv, &cv); af.s[3] = f2bf(part1 + cv * Av0.w + sv * Bv0.w);
    __sincosf(xv1.x, &sv, &cv); af.s[4] = f2bf(part1 + cv * Av1.x + sv * Bv1.x);
    __sincosf(xv1.y, &sv, &cv); af.s[5] = f2bf(part1 + cv * Av1.y + sv * Bv1.y);
    __sincosf(xv1.z, &sv, &cv); af.s[6] = f2bf(part1 + cv * Av1.z + sv * Bv1.z);
    __sincosf(xv1.w, &sv, &cv); af.s[7] = f2bf(part1 + cv * Av1.w + sv * Bv1.w);

    f32x4 acc[7];
    #pragma unroll
    for (int n = 0; n < 7; ++n) acc[n] = (f32x4){0.f, 0.f, 0.f, 0.f};
    #pragma unroll
    for (int n = 0; n < 7; ++n) {
        const bf16x8 bf = *(const bf16x8*)(Wb + (size_t)(n * 16 + l16) * D + gcol);
        acc[n] = __builtin_amdgcn_mfma_f32_16x16x32_bf16(af.v, bf, acc[n], 0, 0, 0);
    }

    float* pb = part + (size_t)j * (BATCH * NCLS);
    #pragma unroll
    for (int n = 0; n < 7; ++n) {
        const int c = n * 16 + l16;
        if (c < NCLS) {
            #pragma unroll
            for (int r = 0; r < 4; ++r)
                pb[(size_t)(m0 + quad * 4 + r) * NCLS + c] = acc[n][r];
        }
    }
}

// ---------------------------------------------------------------------------
// D4: out[b,c] = fcb[c] + sum_j part[j][b][c].  4-lane team per float2 output
// pair: each lane sums 24 of the 96 k-chunks, shfl_xor combine.
// 400 blocks x 256 = 102400 threads = 25600 pairs x 4.
// ---------------------------------------------------------------------------
__global__ __launch_bounds__(256) void reduce_kernel(
        const float* __restrict__ part,             // [KS][512][100] f32
        const float* __restrict__ fcb,
        float* __restrict__ out) {
    const int tid = blockIdx.x * 256 + threadIdx.x;  // 0..102399
    const int p   = tid >> 2;                        // pair 0..25599
    const int g   = tid & 3;                         // k group
    const int b   = p / (NCLS / 2);
    const int c   = (p % (NCLS / 2)) * 2;
    const float* pp = part + (size_t)g * 24 * (BATCH * NCLS) + (size_t)b * NCLS + c;
    float s0 = 0.f, s1 = 0.f;
    #pragma unroll 8
    for (int k = 0; k < 24; ++k) {
        const float2 v = *(const float2*)(pp + (size_t)k * (BATCH * NCLS));
        s0 += v.x; s1 += v.y;
    }
    s0 += __shfl_xor(s0, 1); s0 += __shfl_xor(s0, 2);
    s1 += __shfl_xor(s1, 1); s1 += __shfl_xor(s1, 2);
    if (g == 0)
        *(float2*)(out + (size_t)b * NCLS + c) = make_float2(s0 + fcb[c], s1 + fcb[c + 1]);
}

// ---------------------------------------------------------------------------
// Fallback path (insurance if ws_size < WS_NEED): verified atomic kernels.
// ---------------------------------------------------------------------------
__global__ __launch_bounds__(256) void colsum_atomic_kernel(
        const float* __restrict__ a, const float* __restrict__ b,
        float* __restrict__ ws) {
    const int col  = (blockIdx.x % 3) * 1024 + threadIdx.x * 4;
    const int row0 = (blockIdx.x / 3) * 32;
    float4 sa = make_float4(0.f, 0.f, 0.f, 0.f);
    float4 sb = make_float4(0.f, 0.f, 0.f, 0.f);
    #pragma unroll
    for (int r = 0; r < 32; ++r) {
        const float4 va = *(const float4*)(a + (size_t)(row0 + r) * D + col);
        const float4 vb = *(const float4*)(b + (size_t)(row0 + r) * D + col);
        sa.x += va.x; sa.y += va.y; sa.z += va.z; sa.w += va.w;
        sb.x += vb.x; sb.y += vb.y; sb.z += vb.z; sb.w += vb.w;
    }
    atomicAdd(&ws[col + 0], sa.x); atomicAdd(&ws[col + 1], sa.y);
    atomicAdd(&ws[col + 2], sa.z); atomicAdd(&ws[col + 3], sa.w);
    atomicAdd(&ws[D + col + 0], sb.x); atomicAdd(&ws[D + col + 1], sb.y);
    atomicAdd(&ws[D + col + 2], sb.z); atomicAdd(&ws[D + col + 3], sb.w);
}

__global__ __launch_bounds__(256) void fused_gemm_kernel(
        const float* __restrict__ x,
        const float* __restrict__ w5,
        const float* __restrict__ n5,
        const float* __restrict__ fcw,
        const float* __restrict__ fcb,
        const float* __restrict__ ws,
        float* __restrict__ out) {
    __shared__ __align__(16) float Zl[32 * 36];
    __shared__ __align__(16) float Wl[32 * 132];
    const int t  = threadIdx.x;
    const int bt = blockIdx.x;
    const int j  = blockIdx.y;
    float part1 = 0.f;
    #pragma unroll
    for (int i = 0; i < 4; ++i)
        part1 += w5[i + 1] * n5[i + 1] + w5[i] * n5[i];
    const int c0 = (t & 31) * 4;
    const int b0 = (t >> 5) * 4;
    const int kl = t & 31;
    const int tg = t >> 5;
    const int bbase = bt * 32;
    float acc[4][4];
    #pragma unroll
    for (int i = 0; i < 4; ++i)
        #pragma unroll
        for (int q = 0; q < 4; ++q) acc[i][q] = 0.f;
    for (int s = 0; s < 3; ++s) {
        const int dbase = j * 96 + s * 32;
        for (int idx = t; idx < NCLS * 32; idx += 256) {
            const int c = idx >> 5;
            const int k = idx & 31;
            Wl[k * 132 + c] = fcw[(size_t)c * D + dbase + k];
        }
        const float Av = ws[dbase + kl];
        const float Bv = ws[D + dbase + kl];
        #pragma unroll
        for (int i = 0; i < 4; ++i) {
            const int bl = tg + i * 8;
            const float xv = x[(size_t)(bbase + bl) * D + dbase + kl];
            float sv, cv;
            sincosf(xv, &sv, &cv);
            Zl[bl * 36 + kl] = part1 + cv * Av + sv * Bv;
        }
        __syncthreads();
        #pragma unroll
        for (int k = 0; k < 32; ++k) {
            const float4 wv = *(const float4*)&Wl[k * 132 + c0];
            float zb[4];
            #pragma unroll
            for (int bj = 0; bj < 4; ++bj) zb[bj] = Zl[(b0 + bj) * 36 + k];
            #pragma unroll
            for (int bj = 0; bj < 4; ++bj) {
                acc[bj][0] += zb[bj] * wv.x;
                acc[bj][1] += zb[bj] * wv.y;
                acc[bj][2] += zb[bj] * wv.z;
                acc[bj][3] += zb[bj] * wv.w;
            }
        }
        __syncthreads();
    }
    if (c0 < NCLS) {
        #pragma unroll
        for (int bj = 0; bj < 4; ++bj) {
            const int row = bbase + b0 + bj;
            #pragma unroll
            for (int q = 0; q < 4; ++q) {
                const int c = c0 + q;
                if (c < NCLS) {
                    float v = acc[bj][q];
                    if (j == 0) v += fcb[c];
                    atomicAdd(&out[(size_t)row * NCLS + c], v);
                }
            }
        }
    }
}

extern "C" void kernel_launch(void* const* d_in, const int* in_sizes, int n_in,
                              void* d_out, int out_size, void* d_ws, size_t ws_size,
                              hipStream_t stream) {
    const float* x   = (const float*)d_in[0];
    const float* a   = (const float*)d_in[1];
    const float* b   = (const float*)d_in[2];
    const float* w5  = (const float*)d_in[3];
    const float* n5  = (const float*)d_in[4];
    const float* fcw = (const float*)d_in[5];
    const float* fcb = (const float*)d_in[6];
    float* out = (float*)d_out;
    float* wsf = (float*)d_ws;

    if (ws_size >= WS_NEED) {
        float*          csF  = (float*)((char*)d_ws + WS_OFF_CS);
        unsigned short* Wb   = (unsigned short*)((char*)d_ws + WS_OFF_W);
        float*          partf = (float*)((char*)d_ws + WS_OFF_P);
        prep_kernel<<<dim3(936), 256, 0, stream>>>(a, b, fcw, wsf, Wb);
        csred_kernel<<<dim3(96), 256, 0, stream>>>(wsf, csF);
        fzgemm_kernel<<<dim3(8, KS), 256, 0, stream>>>(x, w5, n5, csF, Wb, partf);
        reduce_kernel<<<dim3(400), 256, 0, stream>>>(partf, fcb, out);
    } else {
        hipMemsetAsync(d_ws, 0, 2 * D * sizeof(float), stream);
        hipMemsetAsync(d_out, 0, (size_t)out_size * sizeof(float), stream);
        colsum_atomic_kernel<<<dim3(288), 256, 0, stream>>>(a, b, wsf);
        fused_gemm_kernel<<<dim3(16, 32), 256, 0, stream>>>(x, w5, n5, fcw, fcb,
                                                            wsf, out);
    }
}

// Round 2
// 128.419 us; speedup vs baseline: 1.0094x; 1.0094x over previous
//
#include <hip/hip_runtime.h>
#include <math.h>

#define D 3072
#define BATCH 512
#define NCLS 100
#define RC12 256          // row-chunks of 12 rows (colsum partial depth)
#define KS 96             // split-k chunks of 32 columns each

typedef __attribute__((ext_vector_type(8))) short bf16x8;
typedef __attribute__((ext_vector_type(4))) float f32x4;

// ws byte layout (fast path):
//   0        : pws  bf16 [2][256][3072]  colsum partials      3145728 B
//   3145728  : csF  f32  [2][3072]       final colsums          24576 B
//   3170304  : Wb   bf16 [112][3072]     fc_w in bf16          688128 B
//   3858432  : part bf16 [96][512][100]  split-k partials     9830400 B
#define WS_OFF_CS  3145728ULL
#define WS_OFF_W   3170304ULL
#define WS_OFF_P   3858432ULL
#define WS_NEED    (WS_OFF_P + (size_t)KS * BATCH * NCLS * 2)

__device__ inline unsigned short f2bf(float f) {
    unsigned u = __float_as_uint(f);
    u += 0x7FFF + ((u >> 16) & 1);          // round-to-nearest-even
    return (unsigned short)(u >> 16);
}
__device__ inline float bf2f(unsigned short s) {
    return __uint_as_float(((unsigned)s) << 16);
}

// ---------------------------------------------------------------------------
// D1 "prep": 936 blocks.
//  blocks [0,768):   colsum partials, 12 rows x 1024 cols each, depth-256,
//                    stored bf16 (ushort4). ~12 waves/CU streaming a+b.
//  blocks [768,936): fc_w fp32 [100][3072] -> bf16 [112][3072] (pad rows 0).
// ---------------------------------------------------------------------------
__global__ __launch_bounds__(256) void prep_kernel(const float* __restrict__ a,
                                                   const float* __restrict__ b,
                                                   const float* __restrict__ fcw,
                                                   unsigned short* __restrict__ pws,
                                                   unsigned short* __restrict__ Wb) {
    const int bid = blockIdx.x;
    const int t   = threadIdx.x;
    if (bid < 768) {
        const int rc   = bid / 3;
        const int cg   = bid % 3;
        const int col  = cg * 1024 + t * 4;
        const int row0 = rc * 12;
        float4 sa = make_float4(0.f, 0.f, 0.f, 0.f);
        float4 sb = make_float4(0.f, 0.f, 0.f, 0.f);
        #pragma unroll
        for (int r = 0; r < 12; ++r) {
            const int i = row0 + r;
            const float4 va = *(const float4*)(a + (size_t)i * D + col);
            const float4 vb = *(const float4*)(b + (size_t)i * D + col);
            sa.x += va.x; sa.y += va.y; sa.z += va.z; sa.w += va.w;
            sb.x += vb.x; sb.y += vb.y; sb.z += vb.z; sb.w += vb.w;
        }
        ushort4 oa, ob;
        oa.x = f2bf(sa.x); oa.y = f2bf(sa.y); oa.z = f2bf(sa.z); oa.w = f2bf(sa.w);
        ob.x = f2bf(sb.x); ob.y = f2bf(sb.y); ob.z = f2bf(sb.z); ob.w = f2bf(sb.w);
        *(ushort4*)(pws + (size_t)rc * D + col)          = oa;
        *(ushort4*)(pws + (size_t)(RC12 + rc) * D + col) = ob;
    } else {
        const int base = ((bid - 768) * 256 + t) * 2;   // float4-item index
        #pragma unroll
        for (int u = 0; u < 2; ++u) {
            const int idx = base + u;                   // 0..86015
            const int c   = idx / (D / 4);
            const int d   = (idx % (D / 4)) * 4;
            ushort4 o;
            if (c < NCLS) {
                const float4 v = *(const float4*)(fcw + (size_t)c * D + d);
                o.x = f2bf(v.x); o.y = f2bf(v.y); o.z = f2bf(v.z); o.w = f2bf(v.w);
            } else {
                o.x = o.y = o.z = o.w = 0;
            }
            *(ushort4*)(Wb + (size_t)c * D + d) = o;
        }
    }
}

// ---------------------------------------------------------------------------
// D2 "csred": reduce depth-256 bf16 partials to final colsum f32 [2][3072].
// 8-lane team per 4-col quad: each lane sums 32 planes (ushort4 loads, 64B-
// contiguous per plane per instruction), then 3x shfl_xor combine.
// 48 blocks x 256 = 12288 threads = 1536 quads x 8.
// ---------------------------------------------------------------------------
__global__ __launch_bounds__(256) void csred_kernel(const unsigned short* __restrict__ pws,
                                                    float* __restrict__ csF) {
    const int tid = blockIdx.x * 256 + threadIdx.x;    // 0..12287
    const int g   = tid & 7;                           // depth group
    const int grp = tid >> 3;                          // col-quad 0..1535
    const int a2  = grp / 768;                         // array (a=0, b=1)
    const int col = (grp % 768) * 4;
    const unsigned short* p = pws + (size_t)(a2 * RC12 + g * 32) * D + col;
    float4 s = make_float4(0.f, 0.f, 0.f, 0.f);
    #pragma unroll 8
    for (int k = 0; k < 32; ++k) {
        const ushort4 v = *(const ushort4*)(p + (size_t)k * D);
        s.x += bf2f(v.x); s.y += bf2f(v.y); s.z += bf2f(v.z); s.w += bf2f(v.w);
    }
    s.x += __shfl_xor(s.x, 1); s.x += __shfl_xor(s.x, 2); s.x += __shfl_xor(s.x, 4);
    s.y += __shfl_xor(s.y, 1); s.y += __shfl_xor(s.y, 2); s.y += __shfl_xor(s.y, 4);
    s.z += __shfl_xor(s.z, 1); s.z += __shfl_xor(s.z, 2); s.z += __shfl_xor(s.z, 4);
    s.w += __shfl_xor(s.w, 1); s.w += __shfl_xor(s.w, 2); s.w += __shfl_xor(s.w, 4);
    if (g == 0)
        *(float4*)(csF + (size_t)a2 * D + col) = s;
}

// ---------------------------------------------------------------------------
// D3 "fzgemm": fused Z-gen + MFMA GEMM, split-K=96, NO LDS, NO prologue.
// Grid (8, 96) x 256 = 768 blocks (12 waves/CU). Each wave: one 16-row x
// 32-col chunk: Z = part1 + cos(x)*A + sin(x)*B on the fly into the A-frag,
// part[j] = Z_chunk x Wb^T via 16x16x32 bf16 MFMA. bf16 partials.
// A/B frag: lane&15 = row/col, k=(lane>>4)*8+j. C/D: col=lane&15,
// row=(lane>>4)*4+reg  [verified earlier session].
// ---------------------------------------------------------------------------
__global__ __launch_bounds__(256) void fzgemm_kernel(
        const float* __restrict__ x,
        const float* __restrict__ w5,
        const float* __restrict__ n5,
        const float* __restrict__ csF,              // [2][3072] final colsums
        const unsigned short* __restrict__ Wb,      // [112][3072] bf16
        unsigned short* __restrict__ part) {        // [KS][512][100] bf16
    const int t    = threadIdx.x;
    const int wave = t >> 6;
    const int lane = t & 63;
    const int l16  = lane & 15;
    const int quad = lane >> 4;
    const int m0   = blockIdx.x * 64 + wave * 16;   // m-tile base (16 rows)
    const int j    = blockIdx.y;                    // k-chunk (32 cols)
    const int gcol = j * 32 + quad * 8;             // this lane's col base

    float part1 = 0.f;
    #pragma unroll
    for (int i = 0; i < 4; ++i)
        part1 += w5[i + 1] * n5[i + 1] + w5[i] * n5[i];

    const float4 Av0 = *(const float4*)(csF + gcol);
    const float4 Av1 = *(const float4*)(csF + gcol + 4);
    const float4 Bv0 = *(const float4*)(csF + D + gcol);
    const float4 Bv1 = *(const float4*)(csF + D + gcol + 4);

    const float* xr = x + (size_t)(m0 + l16) * D;
    const float4 xv0 = *(const float4*)(xr + gcol);
    const float4 xv1 = *(const float4*)(xr + gcol + 4);

    union { bf16x8 v; unsigned short s[8]; } af;
    float sv, cv;
    __sincosf(xv0.x, &sv, &cv); af.s[0] = f2bf(part1 + cv * Av0.x + sv * Bv0.x);
    __sincosf(xv0.y, &sv, &cv); af.s[1] = f2bf(part1 + cv * Av0.y + sv * Bv0.y);
    __sincosf(xv0.z, &sv, &cv); af.s[2] = f2bf(part1 + cv * Av0.z + sv * Bv0.z);
    __sincosf(xv0.w, &sv, &cv); af.s[3] = f2bf(part1 + cv * Av0.w + sv * Bv0.w);
    __sincosf(xv1.x, &sv, &cv); af.s[4] = f2bf(part1 + cv * Av1.x + sv * Bv1.x);
    __sincosf(xv1.y, &sv, &cv); af.s[5] = f2bf(part1 + cv * Av1.y + sv * Bv1.y);
    __sincosf(xv1.z, &sv, &cv); af.s[6] = f2bf(part1 + cv * Av1.z + sv * Bv1.z);
    __sincosf(xv1.w, &sv, &cv); af.s[7] = f2bf(part1 + cv * Av1.w + sv * Bv1.w);

    f32x4 acc[7];
    #pragma unroll
    for (int n = 0; n < 7; ++n) acc[n] = (f32x4){0.f, 0.f, 0.f, 0.f};
    #pragma unroll
    for (int n = 0; n < 7; ++n) {
        const bf16x8 bf = *(const bf16x8*)(Wb + (size_t)(n * 16 + l16) * D + gcol);
        acc[n] = __builtin_amdgcn_mfma_f32_16x16x32_bf16(af.v, bf, acc[n], 0, 0, 0);
    }

    unsigned short* pb = part + (size_t)j * (BATCH * NCLS);
    #pragma unroll
    for (int n = 0; n < 7; ++n) {
        const int c = n * 16 + l16;
        if (c < NCLS) {
            #pragma unroll
            for (int r = 0; r < 4; ++r)
                pb[(size_t)(m0 + quad * 4 + r) * NCLS + c] = f2bf(acc[n][r]);
        }
    }
}

// ---------------------------------------------------------------------------
// D4: out[b,c] = fcb[c] + sum_j part[j][b][c].  4-lane team per bf16x2 pair:
// each lane sums 24 of the 96 k-chunks (uint loads, 64B-contiguous per plane
// per instruction), shfl_xor combine. 400 blocks x 256 = 25600 pairs x 4.
// ---------------------------------------------------------------------------
__global__ __launch_bounds__(256) void reduce_kernel(
        const unsigned int* __restrict__ partu,     // [KS][25600] uint (2xbf16)
        const float* __restrict__ fcb,
        float* __restrict__ out) {
    const int tid = blockIdx.x * 256 + threadIdx.x;  // 0..102399
    const int p   = tid >> 2;                        // pair 0..25599
    const int g   = tid & 3;                         // k group
    const int b   = p / (NCLS / 2);
    const int c   = (p % (NCLS / 2)) * 2;
    const unsigned int* pp = partu + (size_t)g * 24 * (BATCH * NCLS / 2) + p;
    float s0 = 0.f, s1 = 0.f;
    #pragma unroll 8
    for (int k = 0; k < 24; ++k) {
        const unsigned int v = pp[(size_t)k * (BATCH * NCLS / 2)];
        s0 += bf2f((unsigned short)(v & 0xFFFF));
        s1 += bf2f((unsigned short)(v >> 16));
    }
    s0 += __shfl_xor(s0, 1); s0 += __shfl_xor(s0, 2);
    s1 += __shfl_xor(s1, 1); s1 += __shfl_xor(s1, 2);
    if (g == 0)
        *(float2*)(out + (size_t)b * NCLS + c) = make_float2(s0 + fcb[c], s1 + fcb[c + 1]);
}

// ---------------------------------------------------------------------------
// Fallback path (insurance if ws_size < WS_NEED): verified atomic kernels.
// ---------------------------------------------------------------------------
__global__ __launch_bounds__(256) void colsum_atomic_kernel(
        const float* __restrict__ a, const float* __restrict__ b,
        float* __restrict__ ws) {
    const int col  = (blockIdx.x % 3) * 1024 + threadIdx.x * 4;
    const int row0 = (blockIdx.x / 3) * 32;
    float4 sa = make_float4(0.f, 0.f, 0.f, 0.f);
    float4 sb = make_float4(0.f, 0.f, 0.f, 0.f);
    #pragma unroll
    for (int r = 0; r < 32; ++r) {
        const float4 va = *(const float4*)(a + (size_t)(row0 + r) * D + col);
        const float4 vb = *(const float4*)(b + (size_t)(row0 + r) * D + col);
        sa.x += va.x; sa.y += va.y; sa.z += va.z; sa.w += va.w;
        sb.x += vb.x; sb.y += vb.y; sb.z += vb.z; sb.w += vb.w;
    }
    atomicAdd(&ws[col + 0], sa.x); atomicAdd(&ws[col + 1], sa.y);
    atomicAdd(&ws[col + 2], sa.z); atomicAdd(&ws[col + 3], sa.w);
    atomicAdd(&ws[D + col + 0], sb.x); atomicAdd(&ws[D + col + 1], sb.y);
    atomicAdd(&ws[D + col + 2], sb.z); atomicAdd(&ws[D + col + 3], sb.w);
}

__global__ __launch_bounds__(256) void fused_gemm_kernel(
        const float* __restrict__ x,
        const float* __restrict__ w5,
        const float* __restrict__ n5,
        const float* __restrict__ fcw,
        const float* __restrict__ fcb,
        const float* __restrict__ ws,
        float* __restrict__ out) {
    __shared__ __align__(16) float Zl[32 * 36];
    __shared__ __align__(16) float Wl[32 * 132];
    const int t  = threadIdx.x;
    const int bt = blockIdx.x;
    const int j  = blockIdx.y;
    float part1 = 0.f;
    #pragma unroll
    for (int i = 0; i < 4; ++i)
        part1 += w5[i + 1] * n5[i + 1] + w5[i] * n5[i];
    const int c0 = (t & 31) * 4;
    const int b0 = (t >> 5) * 4;
    const int kl = t & 31;
    const int tg = t >> 5;
    const int bbase = bt * 32;
    float acc[4][4];
    #pragma unroll
    for (int i = 0; i < 4; ++i)
        #pragma unroll
        for (int q = 0; q < 4; ++q) acc[i][q] = 0.f;
    for (int s = 0; s < 3; ++s) {
        const int dbase = j * 96 + s * 32;
        for (int idx = t; idx < NCLS * 32; idx += 256) {
            const int c = idx >> 5;
            const int k = idx & 31;
            Wl[k * 132 + c] = fcw[(size_t)c * D + dbase + k];
        }
        const float Av = ws[dbase + kl];
        const float Bv = ws[D + dbase + kl];
        #pragma unroll
        for (int i = 0; i < 4; ++i) {
            const int bl = tg + i * 8;
            const float xv = x[(size_t)(bbase + bl) * D + dbase + kl];
            float sv, cv;
            sincosf(xv, &sv, &cv);
            Zl[bl * 36 + kl] = part1 + cv * Av + sv * Bv;
        }
        __syncthreads();
        #pragma unroll
        for (int k = 0; k < 32; ++k) {
            const float4 wv = *(const float4*)&Wl[k * 132 + c0];
            float zb[4];
            #pragma unroll
            for (int bj = 0; bj < 4; ++bj) zb[bj] = Zl[(b0 + bj) * 36 + k];
            #pragma unroll
            for (int bj = 0; bj < 4; ++bj) {
                acc[bj][0] += zb[bj] * wv.x;
                acc[bj][1] += zb[bj] * wv.y;
                acc[bj][2] += zb[bj] * wv.z;
                acc[bj][3] += zb[bj] * wv.w;
            }
        }
        __syncthreads();
    }
    if (c0 < NCLS) {
        #pragma unroll
        for (int bj = 0; bj < 4; ++bj) {
            const int row = bbase + b0 + bj;
            #pragma unroll
            for (int q = 0; q < 4; ++q) {
                const int c = c0 + q;
                if (c < NCLS) {
                    float v = acc[bj][q];
                    if (j == 0) v += fcb[c];
                    atomicAdd(&out[(size_t)row * NCLS + c], v);
                }
            }
        }
    }
}

extern "C" void kernel_launch(void* const* d_in, const int* in_sizes, int n_in,
                              void* d_out, int out_size, void* d_ws, size_t ws_size,
                              hipStream_t stream) {
    const float* x   = (const float*)d_in[0];
    const float* a   = (const float*)d_in[1];
    const float* b   = (const float*)d_in[2];
    const float* w5  = (const float*)d_in[3];
    const float* n5  = (const float*)d_in[4];
    const float* fcw = (const float*)d_in[5];
    const float* fcb = (const float*)d_in[6];
    float* out = (float*)d_out;
    float* wsf = (float*)d_ws;

    if (ws_size >= WS_NEED) {
        unsigned short* pws  = (unsigned short*)d_ws;
        float*          csF  = (float*)((char*)d_ws + WS_OFF_CS);
        unsigned short* Wb   = (unsigned short*)((char*)d_ws + WS_OFF_W);
        unsigned short* partb = (unsigned short*)((char*)d_ws + WS_OFF_P);
        prep_kernel<<<dim3(936), 256, 0, stream>>>(a, b, fcw, pws, Wb);
        csred_kernel<<<dim3(48), 256, 0, stream>>>(pws, csF);
        fzgemm_kernel<<<dim3(8, KS), 256, 0, stream>>>(x, w5, n5, csF, Wb, partb);
        reduce_kernel<<<dim3(400), 256, 0, stream>>>((const unsigned int*)partb,
                                                     fcb, out);
    } else {
        hipMemsetAsync(d_ws, 0, 2 * D * sizeof(float), stream);
        hipMemsetAsync(d_out, 0, (size_t)out_size * sizeof(float), stream);
        colsum_atomic_kernel<<<dim3(288), 256, 0, stream>>>(a, b, wsf);
        fused_gemm_kernel<<<dim3(16, 32), 256, 0, stream>>>(x, w5, n5, fcw, fcb,
                                                            wsf, out);
    }
}